// Round 1
// 126.973 us; speedup vs baseline: 1.0173x; 1.0173x over previous
//
#include <hip/hip_runtime.h>
#include <stdint.h>

// Problem constants (fixed by reference setup_inputs)
#define BB 2
#define NN 16384
#define MM 4096
#define CC 64
#define KK 16
#define NQ (BB * MM)
#define NF4 (NN / 4)

// Fused kNN config: block = QW queries (x-adjacent after query sort) x 4 waves
#define QW 4
#define NBIN 512         // 1/32-octave bins over d^2 in [2^-8, 2^8]
#define SHIFT 18
#define BOFF 12000       // fkey(2^-8) >> 18
#define CAP 192          // per-query collect capacity (new E ~17-60)
#define NSLAB 256

typedef unsigned long long u64;

// Monotone uint key for float ordering (handles negative-from-cancellation)
static __device__ __forceinline__ unsigned fkey(float d) {
    unsigned u = __float_as_uint(d);
    return u ^ (unsigned)(((int)u >> 31) | (int)0x80000000u);
}

// Monotone x -> slab via algebraic sigmoid (t2-CDF-ish equal-ish-count bins).
// Cross-kernel consistency for POINTS is guaranteed by storing the slab id
// (pslab/qslab); the query-window side tolerates +-1 ulp jitter via the
// +-1 slab expansion in knn_kernel.
static __device__ __forceinline__ int slab_of(float x) {
    float u = x * rsqrtf(fmaf(x, x, 4.0f));     // in (-1,1), monotone
    int s = (int)fmaf(u, 128.0f, 128.0f);
    return s < 0 ? 0 : (s > NSLAB - 1 ? NSLAB - 1 : s);
}

// RNE fp32 -> bf16 pair packed into one uint (lo = a, hi = b)
static __device__ __forceinline__ unsigned pack_bf16(float a, float b) {
    unsigned ua = __float_as_uint(a), ub = __float_as_uint(b);
    ua = (ua + 0x7fffu + ((ua >> 16) & 1u)) >> 16;
    ub = (ub + 0x7fffu + ((ub >> 16) & 1u)) & 0xffff0000u;
    return ua | ub;
}

// ---------- prep: blocks [0,512) transpose x1->bf16 xt; [512,544) bin pts+queries ----------
__global__ __launch_bounds__(256)
void prep_kernel(const float* __restrict__ p1, const float* __restrict__ x1,
                 const float* __restrict__ p2,
                 unsigned* __restrict__ ghist, unsigned* __restrict__ qhist,
                 unsigned char* __restrict__ pslab, unsigned char* __restrict__ qslab,
                 unsigned* __restrict__ xt32, int has_xt) {
    const int t = threadIdx.x;
    if (blockIdx.x >= 512) {
        // count pass of the slab counting sort (points + queries)
        int u = (blockIdx.x - 512) * 256 + t;          // 8192 threads
        const float4* src = (const float4*)(p1 + (size_t)u * 12);
        float4 a = src[0], b4 = src[1], c4 = src[2];
        // x coords of the 4 points: a.x, a.w, b4.z, c4.y
        const int pbase = u * 4;
        const int bb = pbase >> 14;                    // batch
        unsigned s0 = (unsigned)slab_of(a.x);
        unsigned s1 = (unsigned)slab_of(a.w);
        unsigned s2 = (unsigned)slab_of(b4.z);
        unsigned s3 = (unsigned)slab_of(c4.y);
        atomicAdd(&ghist[bb * NSLAB + s0], 1u);
        atomicAdd(&ghist[bb * NSLAB + s1], 1u);
        atomicAdd(&ghist[bb * NSLAB + s2], 1u);
        atomicAdd(&ghist[bb * NSLAB + s3], 1u);
        *(unsigned*)(pslab + pbase) = s0 | (s1 << 8) | (s2 << 16) | (s3 << 24);
        // one query per thread (8192 queries total)
        float qxv = p2[(size_t)u * 3];
        unsigned sq = (unsigned)slab_of(qxv);
        atomicAdd(&qhist[(u >> 12) * NSLAB + sq], 1u);
        qslab[u] = (unsigned char)sq;
        return;
    }
    if (!has_xt) return;
    // transpose tile: x1 (B,C,N) f32 -> xt (B,N,C) bf16
    __shared__ float lds[64 * 65];
    const int bi = blockIdx.x;
    const int b  = bi >> 8;                  // 256 n-tiles per batch
    const int n0 = (bi & 255) << 6;
    const float* src = x1 + (size_t)b * CC * NN;
    #pragma unroll
    for (int r = 0; r < 16; ++r) {
        int c = r * 4 + (t >> 6);
        int n = t & 63;
        lds[n * 65 + c] = src[(size_t)c * NN + n0 + n];   // coalesced read
    }
    __syncthreads();
    unsigned* dst = xt32 + ((size_t)b * NN + n0) * 32;    // 32 uints per point row
    #pragma unroll
    for (int r = 0; r < 8; ++r) {
        int idx = r * 256 + t;
        int n = idx >> 5, cu = idx & 31;
        dst[(size_t)n * 32 + cu] =
            pack_bf16(lds[n * 65 + cu * 2], lds[n * 65 + cu * 2 + 1]);
    }
}

// ---------- scatter: redundant LDS scan of counts, then counting-sort scatter ----------
__global__ __launch_bounds__(256)
void scatter_kernel(const float* __restrict__ p1,
                    const unsigned* __restrict__ ghist, unsigned* __restrict__ gcur,
                    const unsigned* __restrict__ qhist, unsigned* __restrict__ qcur,
                    const unsigned char* __restrict__ pslab,
                    const unsigned char* __restrict__ qslab,
                    int* __restrict__ slabSt,
                    float* __restrict__ xs, float* __restrict__ ys,
                    float* __restrict__ zs, float* __restrict__ ns,
                    int* __restrict__ orig, int* __restrict__ qperm) {
    __shared__ unsigned sg[1024];   // [pts b0 | pts b1 | q b0 | q b1], inclusive scans
    const int t = threadIdx.x;
    for (int i = t; i < 1024; i += 256)
        sg[i] = (i < 512) ? ghist[i] : qhist[i - 512];
    __syncthreads();
    for (int off = 1; off < 256; off <<= 1) {
        unsigned addv[4];
        #pragma unroll
        for (int r = 0; r < 4; ++r)
            addv[r] = (t >= off) ? sg[r * 256 + t - off] : 0u;
        __syncthreads();
        #pragma unroll
        for (int r = 0; r < 4; ++r) sg[r * 256 + t] += addv[r];
        __syncthreads();
    }
    if (blockIdx.x == 0) {
        // exclusive starts; [b][256] = NN
        slabSt[t + 1]       = (int)sg[t];
        slabSt[257 + t + 1] = (int)sg[256 + t];
        if (t == 0) { slabSt[0] = 0; slabSt[257] = 0; }
    }
    // scatter 4 points + 1 query per thread (same mapping as prep count pass)
    const int u = blockIdx.x * 256 + t;      // 0..8191
    const float4* src = (const float4*)(p1 + (size_t)u * 12);
    float4 a = src[0], b4 = src[1], c4 = src[2];
    float X[4] = {a.x, a.w, b4.z, c4.y};
    float Y[4] = {a.y, b4.x, b4.w, c4.z};
    float Z[4] = {a.z, b4.y, c4.x, c4.w};
    const int pbase = u * 4;
    const int bb = pbase >> 14;
    const unsigned packed = *(const unsigned*)(pslab + pbase);
    #pragma unroll
    for (int i = 0; i < 4; ++i) {
        const int s = (int)((packed >> (8 * i)) & 255u);
        const unsigned start = s ? sg[bb * 256 + s - 1] : 0u;
        const unsigned pos = start + atomicAdd(&gcur[bb * 256 + s], 1u);
        const size_t o = (size_t)bb * NN + pos;
        xs[o] = X[i]; ys[o] = Y[i]; zs[o] = Z[i];
        ns[o] = fmaf(X[i], X[i], fmaf(Y[i], Y[i], Z[i] * Z[i]));
        orig[o] = (pbase + i) & (NN - 1);    // LOCAL original index (tie-break + gather)
    }
    const int qb = u >> 12;
    const int sq = (int)qslab[u];
    const unsigned qstart = sq ? sg[512 + qb * 256 + sq - 1] : 0u;
    const unsigned qpos = qstart + atomicAdd(&qcur[qb * 256 + sq], 1u);
    qperm[qb * MM + qpos] = u & (MM - 1);    // local query index, sorted by slab
}

// ---------- fused kNN: slab-window bound -> collect -> select -> gather ----------
__global__ __launch_bounds__(256, 4)
void knn_kernel(const float* __restrict__ xs, const float* __restrict__ ys,
                const float* __restrict__ zs, const float* __restrict__ ns,
                const int* __restrict__ orig, const int* __restrict__ qperm,
                const int* __restrict__ slabSt, const float* __restrict__ p2,
                const unsigned* __restrict__ xt32,
                int* __restrict__ idx_ws, float* __restrict__ out) {
    __shared__ unsigned hist[QW * NBIN];   // 8 KB
    __shared__ u64 col[QW * CAP];          // 6 KB
    __shared__ unsigned colcnt[QW];
    __shared__ float bound_s[QW];
    __shared__ int sel[QW][KK];
    __shared__ float fmean[QW][CC];

    const int t = threadIdx.x;
    const int w = t >> 6;
    const int l = t & 63;
    const int bblk = blockIdx.x >> 10;             // batch (1024 blocks each)
    const int qb4  = (blockIdx.x & 1023) * QW;
    const int* QP  = qperm + bblk * MM;
    const int* SST = slabSt + bblk * 257;
    const float4* X4 = (const float4*)xs + (size_t)bblk * NF4;
    const float4* Y4 = (const float4*)ys + (size_t)bblk * NF4;
    const float4* Z4 = (const float4*)zs + (size_t)bblk * NF4;
    const float4* N4 = (const float4*)ns + (size_t)bblk * NF4;
    const int* ORG = orig + (size_t)bblk * NN;

    float qx[QW], ax[QW], ay[QW], az[QW], qn[QW];
    #pragma unroll
    for (int j = 0; j < QW; ++j) {
        int ql = QP[qb4 + j];
        const float* qp = p2 + ((size_t)bblk * MM + ql) * 3;
        float x = qp[0], y = qp[1], z = qp[2];
        qx[j] = x;
        ax[j] = -2.0f * x; ay[j] = -2.0f * y; az[j] = -2.0f * z;
        qn[j] = fmaf(x, x, fmaf(y, y, z * z));
    }

    #pragma unroll
    for (int i = t; i < QW * NBIN; i += 256) hist[i] = 0u;
    if (t < QW) colcnt[t] = 0u;
    __syncthreads();

    // same distance expression everywhere (bound pass and collect pass)
    #define DISTJ(j, xv, yv, zv, nv) \
        (fmaf(ax[j], xv, fmaf(ay[j], yv, fmaf(az[j], zv, nv))) + qn[j])

    // ---- phase 1: histogram the 2048 x-nearest points (valid-subset bound) ----
    {
        int pos = SST[slab_of(qx[0])];
        int S = pos - 1024;
        S = S < 0 ? 0 : (S > NN - 2048 ? NN - 2048 : S);
        const int S4 = S >> 2;
        #define H1(xv, yv, zv, nv)                                              \
        {   _Pragma("unroll")                                                   \
            for (int j = 0; j < QW; ++j) {                                      \
                float d = DISTJ(j, xv, yv, zv, nv);                             \
                int bin = (int)(fkey(d) >> SHIFT) - BOFF;                       \
                bin = bin < 0 ? 0 : (bin > NBIN - 1 ? NBIN - 1 : bin);          \
                atomicAdd(&hist[j * NBIN + bin], 1u);                           \
            } }
        #pragma unroll
        for (int it = 0; it < 2; ++it) {
            int f = S4 + it * 256 + w * 64 + l;
            float4 X = X4[f], Y = Y4[f], Z = Z4[f], Nr = N4[f];
            H1(X.x, Y.x, Z.x, Nr.x) H1(X.y, Y.y, Z.y, Nr.y)
            H1(X.z, Y.z, Z.z, Nr.z) H1(X.w, Y.w, Z.w, Nr.w)
        }
        #undef H1
    }
    __syncthreads();

    // ---- beta for query w (one query per wave) ----
    {
        const unsigned hb = w * NBIN;
        unsigned c8[8], s = 0;
        #pragma unroll
        for (int i = 0; i < 8; ++i) { c8[i] = hist[hb + l * 8 + i]; s += c8[i]; }
        unsigned pre = s;
        #pragma unroll
        for (int off = 1; off < 64; off <<= 1) {
            unsigned o = __shfl_up(pre, off, 64);
            if (l >= off) pre += o;
        }
        unsigned excl = pre - s;
        int bsel = 0x7fffffff;
        if (excl < KK) {
            unsigned cum = excl;
            #pragma unroll
            for (int i = 0; i < 8; ++i) {
                if (cum < KK && cum + c8[i] >= KK) bsel = l * 8 + i;
                cum += c8[i];
            }
        }
        #pragma unroll
        for (int off = 32; off; off >>= 1) {
            int o = __shfl_xor(bsel, off, 64);
            bsel = o < bsel ? o : bsel;
        }
        if (bsel == 0x7fffffff) bsel = NBIN - 1;
        if (l == 0)
            bound_s[w] = __uint_as_float(
                (((unsigned)(bsel + BOFF + 1)) << SHIFT) & 0x7fffffffu);
    }
    __syncthreads();
    float bnd[QW];
    #pragma unroll
    for (int j = 0; j < QW; ++j) bnd[j] = bound_s[j];

    // ---- window: union over 4 queries of [qx - sqrt(bnd), qx + sqrt(bnd)] ----
    float wl = 1e30f, wh = -1e30f;
    #pragma unroll
    for (int j = 0; j < QW; ++j) {
        float b = sqrtf(bnd[j]);
        wl = fminf(wl, qx[j] - b);
        wh = fmaxf(wh, qx[j] + b);
    }
    int sLo = slab_of(wl) - 1; sLo = sLo < 0 ? 0 : sLo;          // +-1 slab safety
    int sHi = slab_of(wh) + 1; sHi = sHi > NSLAB - 1 ? NSLAB - 1 : sHi;
    const int F0 = SST[sLo] >> 2;
    int F1 = (SST[sHi + 1] + 3) >> 2;
    F1 = F1 > NF4 ? NF4 : F1;

    // ---- phase 2: scan window only, collect d < bnd[j] ----
    #define PUSH(j, dv, p)                                                      \
    {   unsigned key = fkey(dv);                                                \
        int oid = ORG[(p)];                                                     \
        unsigned slot = atomicAdd(&colcnt[j], 1u);                              \
        slot = slot < CAP ? slot : CAP - 1;                                     \
        col[(j) * CAP + slot] = ((u64)key << 32) | (unsigned)oid; }

    const int nIt = (F1 - F0 + 255) >> 8;
    #pragma unroll 1
    for (int it = 0; it < nIt; ++it) {
        int f = F0 + it * 256 + w * 64 + l;
        if (f < F1) {
            float4 X = X4[f], Y = Y4[f], Z = Z4[f], Nr = N4[f];
            #pragma unroll
            for (int j = 0; j < QW; ++j) {
                float d0 = DISTJ(j, X.x, Y.x, Z.x, Nr.x);
                float d1 = DISTJ(j, X.y, Y.y, Z.y, Nr.y);
                float d2 = DISTJ(j, X.z, Y.z, Z.z, Nr.z);
                float d3 = DISTJ(j, X.w, Y.w, Z.w, Nr.w);
                float mn = fminf(fminf(d0, d1), fminf(d2, d3));
                if (mn < bnd[j]) {
                    if (d0 < bnd[j]) PUSH(j, d0, f * 4 + 0)
                    if (d1 < bnd[j]) PUSH(j, d1, f * 4 + 1)
                    if (d2 < bnd[j]) PUSH(j, d2, f * 4 + 2)
                    if (d3 < bnd[j]) PUSH(j, d3, f * 4 + 3)
                }
            }
        }
    }
    #undef PUSH
    #undef DISTJ
    __syncthreads();

    // ---- select for query w: exact top-16 on (key, orig-idx) ----
    {
        unsigned cnt = colcnt[w]; cnt = cnt < CAP ? cnt : CAP;
        if (cnt <= 64u) {
            // rank scan: broadcast LDS reads, unique ranks (keys distinct via idx)
            u64 v = ((unsigned)l < cnt) ? col[w * CAP + l] : ~0ull;
            int rank = 0;
            for (unsigned i = 0; i < cnt; ++i)
                rank += (col[w * CAP + i] < v) ? 1 : 0;
            if ((unsigned)l < cnt && rank < KK) {
                int id = (int)(unsigned)(v & 0xFFFFFFFFull);
                if (xt32) sel[w][rank] = id;
                else {
                    int qlw = QP[qb4 + w];
                    idx_ws[((size_t)bblk * MM + qlw) * KK + rank] = id;
                }
            }
        } else {
            u64 v0 = ((unsigned)l       < cnt) ? col[w * CAP + l]       : ~0ull;
            u64 v1 = ((unsigned)l + 64  < cnt) ? col[w * CAP + l + 64]  : ~0ull;
            u64 v2 = ((unsigned)l + 128 < cnt) ? col[w * CAP + l + 128] : ~0ull;
            #pragma unroll 1
            for (int k = 0; k < KK; ++k) {
                u64 m = v0 < v1 ? v0 : v1;
                m = v2 < m ? v2 : m;
                #pragma unroll
                for (int off = 32; off; off >>= 1) {
                    u64 o = __shfl_xor(m, off, 64);
                    m = o < m ? o : m;
                }
                if (v0 == m) v0 = ~0ull;
                if (v1 == m) v1 = ~0ull;
                if (v2 == m) v2 = ~0ull;
                if (l == 0) {
                    int id = (m == ~0ull) ? 0 : (int)(unsigned)(m & 0xFFFFFFFFull);
                    if (xt32) sel[w][k] = id;
                    else {
                        int qlw = QP[qb4 + w];
                        idx_ws[((size_t)bblk * MM + qlw) * KK + k] = id;
                    }
                }
            }
        }
    }
    if (!xt32) return;
    __syncthreads();

    // ---- fused gather from bf16 xt: one wave per query, 4-way k-split ----
    {
        const int cg = l & 15;                 // 4-channel group (uint2 = 8B bf16)
        const int h  = l >> 4;                 // neighbor quarter 0..3
        const unsigned* xb = xt32 + (size_t)bblk * NN * 32 + cg * 2;
        float a0 = 0.f, a1 = 0.f, a2 = 0.f, a3 = 0.f;
        #pragma unroll
        for (int k = 0; k < 4; ++k) {
            int n = sel[w][h * 4 + k];
            uint2 v = *(const uint2*)(xb + (size_t)n * 32);
            a0 += __uint_as_float(v.x << 16);
            a1 += __uint_as_float(v.x & 0xffff0000u);
            a2 += __uint_as_float(v.y << 16);
            a3 += __uint_as_float(v.y & 0xffff0000u);
        }
        a0 += __shfl_xor(a0, 16, 64); a0 += __shfl_xor(a0, 32, 64);
        a1 += __shfl_xor(a1, 16, 64); a1 += __shfl_xor(a1, 32, 64);
        a2 += __shfl_xor(a2, 16, 64); a2 += __shfl_xor(a2, 32, 64);
        a3 += __shfl_xor(a3, 16, 64); a3 += __shfl_xor(a3, 32, 64);
        if (h == 0) {
            fmean[w][cg * 4 + 0] = a0; fmean[w][cg * 4 + 1] = a1;
            fmean[w][cg * 4 + 2] = a2; fmean[w][cg * 4 + 3] = a3;
        }
    }
    __syncthreads();
    {
        const float sc = 1.0f / 16.0f;
        float* ob = out + (size_t)bblk * CC * MM;
        int c = t >> 2;
        int qlj = QP[qb4 + (t & 3)];           // scattered 4B store per query
        ob[(size_t)c * MM + qlj] = fmean[t & 3][c] * sc;
    }
}

// ---------- fallback gather (no xt room): column gather from x1 ----------
#define GM 64
__global__ __launch_bounds__(256)
void gather_kernel(const float* __restrict__ x1, const int* __restrict__ idx_ws,
                   float* __restrict__ out) {
    __shared__ int lidx[KK * GM];
    const int t = threadIdx.x;
    const int mblk = blockIdx.x >> 2;
    const int cblk = blockIdx.x & 3;
    const int m0 = mblk * GM;
    for (int e = t; e < KK * GM; e += 256) {
        int val = idx_ws[m0 * KK + e];
        lidx[(e & 15) * GM + (e >> 4)] = val;
    }
    __syncthreads();
    const int ml = t & 63;
    const int q = m0 + ml, b = q >> 12, mm = q & (MM - 1);
    const float* xb = x1 + (size_t)b * CC * NN;
    float* ob = out + (size_t)b * CC * MM;
    #pragma unroll 1
    for (int r = 0; r < 4; ++r) {
        int c = cblk * 16 + (t >> 6) * 4 + r;
        const float* xc = xb + (size_t)c * NN;
        float acc = 0.f;
        #pragma unroll
        for (int k = 0; k < KK; ++k) acc += xc[lidx[k * GM + ml]];
        ob[(size_t)c * MM + mm] = acc * (1.0f / 16.0f);
    }
}

extern "C" void kernel_launch(void* const* d_in, const int* in_sizes, int n_in,
                              void* d_out, int out_size, void* d_ws, size_t ws_size,
                              hipStream_t stream) {
    const float* p1 = (const float*)d_in[0];   // (B,N,3)
    const float* x1 = (const float*)d_in[1];   // (B,C,N)
    const float* p2 = (const float*)d_in[2];   // (B,M,3)
    float* out = (float*)d_out;                // (B,C,M)

    char* ws = (char*)d_ws;
    // sorted SoA: xs,ys,zs,ns each BB*NN floats = 512 KB total
    float* xs  = (float*)ws;
    float* ysv = xs + BB * NN;
    float* zsv = ysv + BB * NN;
    float* nsv = zsv + BB * NN;
    int* orig  = (int*)(ws + 524288);                    // 128 KB
    int* qperm = (int*)(ws + 655360);                    // 32 KB
    unsigned char* pslab = (unsigned char*)(ws + 688128);// 32 KB
    unsigned char* qslab = (unsigned char*)(ws + 720896);// 8 KB
    unsigned* ctrl = (unsigned*)(ws + 729088);           // 8 KB zeroed
    unsigned* ghist = ctrl;
    unsigned* gcur  = ctrl + 512;
    unsigned* qhist = ctrl + 1024;
    unsigned* qcur  = ctrl + 1536;
    int* slabSt = (int*)(ws + 737280);                   // 2*257 ints (padded 4 KB)
    const size_t xt_off   = 741376;
    const size_t xt_bytes = (size_t)BB * NN * CC * 2;    // 4.19 MB bf16
    const bool use_t = ws_size >= xt_off + xt_bytes;
    unsigned* xt32 = use_t ? (unsigned*)(ws + xt_off) : nullptr;
    int* idx_ws = use_t ? nullptr : (int*)(ws + xt_off); // 512 KB fallback

    hipMemsetAsync(ctrl, 0, 8192, stream);
    prep_kernel<<<544, 256, 0, stream>>>(p1, x1, p2, ghist, qhist, pslab, qslab,
                                         xt32, use_t ? 1 : 0);
    scatter_kernel<<<32, 256, 0, stream>>>(p1, ghist, gcur, qhist, qcur,
                                           pslab, qslab, slabSt,
                                           xs, ysv, zsv, nsv, orig, qperm);
    knn_kernel<<<NQ / QW, 256, 0, stream>>>(xs, ysv, zsv, nsv, orig, qperm,
                                            slabSt, p2, xt32, idx_ws, out);
    if (!use_t)
        gather_kernel<<<(NQ / GM) * 4, 256, 0, stream>>>(x1, idx_ws, out);
}

// Round 3
// 113.235 us; speedup vs baseline: 1.1408x; 1.1213x over previous
//
#include <hip/hip_runtime.h>
#include <stdint.h>

// Problem constants (fixed by reference setup_inputs)
#define BB 2
#define NN 16384
#define MM 4096
#define CC 64
#define KK 16
#define NQ (BB * MM)
#define NF4 (NN / 4)

// Fused kNN config: block = QW queries (x-adjacent after query sort) x 4 waves
#define QW 4
#define NBIN 512         // 1/32-octave bins over d^2 in [2^-8, 2^8]
#define SHIFT 18
#define BOFF 12000       // fkey(2^-8) >> 18
#define CAP 192          // per-query collect capacity
#define NSLAB 256

typedef unsigned long long u64;

// Monotone uint key for float ordering (handles negative-from-cancellation)
static __device__ __forceinline__ unsigned fkey(float d) {
    unsigned u = __float_as_uint(d);
    return u ^ (unsigned)(((int)u >> 31) | (int)0x80000000u);
}

// Monotone x -> slab via algebraic sigmoid (equal-ish-count bins for N(0,1)).
// Cross-kernel consistency for POINTS is guaranteed by storing the slab id
// (pslab/qslab); the query-window side tolerates +-1 ulp jitter via the
// +-1 slab expansion in knn_kernel.
static __device__ __forceinline__ int slab_of(float x) {
    float u = x * rsqrtf(fmaf(x, x, 4.0f));     // in (-1,1), monotone
    int s = (int)fmaf(u, 128.0f, 128.0f);
    return s < 0 ? 0 : (s > NSLAB - 1 ? NSLAB - 1 : s);
}

// RNE fp32 -> bf16 pair packed into one uint (lo = a, hi = b)
static __device__ __forceinline__ unsigned pack_bf16(float a, float b) {
    unsigned ua = __float_as_uint(a), ub = __float_as_uint(b);
    ua = (ua + 0x7fffu + ((ua >> 16) & 1u)) >> 16;
    ub = (ub + 0x7fffu + ((ub >> 16) & 1u)) & 0xffff0000u;
    return ua | ub;
}

// ---------- prep: blocks [0,512) transpose x1->bf16 xt; [512,544) bin pts+queries ----------
// Binning uses per-block LDS partial hists -> no global atomics, no pre-zeroed
// memory needed (removes the hipMemsetAsync dispatch). gcur/qcur (consumed only
// by the later scatter kernel) are zeroed by binning blocks 0 and 1.
__global__ __launch_bounds__(256)
void prep_kernel(const float* __restrict__ p1, const float* __restrict__ x1,
                 const float* __restrict__ p2,
                 unsigned* __restrict__ ppart, unsigned* __restrict__ qpart,
                 unsigned* __restrict__ gcur, unsigned* __restrict__ qcur,
                 unsigned char* __restrict__ pslab, unsigned char* __restrict__ qslab,
                 unsigned* __restrict__ xt32, int has_xt) {
    const int t = threadIdx.x;
    if (blockIdx.x >= 512) {
        const int k = blockIdx.x - 512;                // 0..31 binning block
        __shared__ unsigned ph[NSLAB], qh[NSLAB];
        ph[t] = 0u; qh[t] = 0u;
        __syncthreads();
        const int u = k * 256 + t;                     // 8192 threads
        const float4* src = (const float4*)(p1 + (size_t)u * 12);
        float4 a = src[0], b4 = src[1], c4 = src[2];
        // x coords of the 4 points: a.x, a.w, b4.z, c4.y
        const int pbase = u * 4;
        unsigned s0 = (unsigned)slab_of(a.x);
        unsigned s1 = (unsigned)slab_of(a.w);
        unsigned s2 = (unsigned)slab_of(b4.z);
        unsigned s3 = (unsigned)slab_of(c4.y);
        atomicAdd(&ph[s0], 1u); atomicAdd(&ph[s1], 1u);
        atomicAdd(&ph[s2], 1u); atomicAdd(&ph[s3], 1u);
        *(unsigned*)(pslab + pbase) = s0 | (s1 << 8) | (s2 << 16) | (s3 << 24);
        // one query per thread (8192 queries total, same batch as block's points)
        float qxv = p2[(size_t)u * 3];
        unsigned sq = (unsigned)slab_of(qxv);
        atomicAdd(&qh[sq], 1u);
        qslab[u] = (unsigned char)sq;
        __syncthreads();
        ppart[k * NSLAB + t] = ph[t];
        qpart[k * NSLAB + t] = qh[t];
        if (k == 0) { gcur[t] = 0u; gcur[256 + t] = 0u; }
        if (k == 1) { qcur[t] = 0u; qcur[256 + t] = 0u; }
        return;
    }
    if (!has_xt) return;
    // transpose tile: x1 (B,C,N) f32 -> xt (B,N,C) bf16
    __shared__ float lds[64 * 65];
    const int bi = blockIdx.x;
    const int b  = bi >> 8;                  // 256 n-tiles per batch
    const int n0 = (bi & 255) << 6;
    const float* src = x1 + (size_t)b * CC * NN;
    #pragma unroll
    for (int r = 0; r < 16; ++r) {
        int c = r * 4 + (t >> 6);
        int n = t & 63;
        lds[n * 65 + c] = src[(size_t)c * NN + n0 + n];   // coalesced read
    }
    __syncthreads();
    unsigned* dst = xt32 + ((size_t)b * NN + n0) * 32;    // 32 uints per point row
    #pragma unroll
    for (int r = 0; r < 8; ++r) {
        int idx = r * 256 + t;
        int n = idx >> 5, cu = idx & 31;
        dst[(size_t)n * 32 + cu] =
            pack_bf16(lds[n * 65 + cu * 2], lds[n * 65 + cu * 2 + 1]);
    }
}

// ---------- scatter: reduce partials + LDS scan, then counting-sort scatter ----------
// Blocks [0,32): points (4/thread). Blocks [32,64): queries (1/thread).
// Within-slab order is nondeterministic (atomic) but irrelevant: selection
// tie-breaks on the composite (key, orig-idx) which is order-invariant.
__global__ __launch_bounds__(256)
void scatter_kernel(const float* __restrict__ p1,
                    const unsigned* __restrict__ ppart, const unsigned* __restrict__ qpart,
                    unsigned* __restrict__ gcur, unsigned* __restrict__ qcur,
                    const unsigned char* __restrict__ pslab,
                    const unsigned char* __restrict__ qslab,
                    int* __restrict__ slabSt,
                    float* __restrict__ xs, float* __restrict__ ys,
                    float* __restrict__ zs, float* __restrict__ ns,
                    int* __restrict__ orig, int* __restrict__ qperm) {
    __shared__ unsigned sg[1024];   // [pts b0 | pts b1 | q b0 | q b1], inclusive scans
    const int t = threadIdx.x;
    {
        unsigned a0 = 0, a1 = 0, a2 = 0, a3 = 0;
        #pragma unroll
        for (int k = 0; k < 16; ++k) {
            a0 += ppart[k * NSLAB + t];
            a1 += ppart[(16 + k) * NSLAB + t];
            a2 += qpart[k * NSLAB + t];
            a3 += qpart[(16 + k) * NSLAB + t];
        }
        sg[t] = a0; sg[256 + t] = a1; sg[512 + t] = a2; sg[768 + t] = a3;
    }
    __syncthreads();
    for (int off = 1; off < 256; off <<= 1) {
        unsigned addv[4];
        #pragma unroll
        for (int r = 0; r < 4; ++r)
            addv[r] = (t >= off) ? sg[r * 256 + t - off] : 0u;
        __syncthreads();
        #pragma unroll
        for (int r = 0; r < 4; ++r) sg[r * 256 + t] += addv[r];
        __syncthreads();
    }
    if (blockIdx.x == 0) {
        // exclusive starts; [b][256] = NN
        slabSt[t + 1]       = (int)sg[t];
        slabSt[257 + t + 1] = (int)sg[256 + t];
        if (t == 0) { slabSt[0] = 0; slabSt[257] = 0; }
    }
    if (blockIdx.x < 32) {
        // scatter 4 points per thread (same mapping as prep count pass)
        const int u = blockIdx.x * 256 + t;      // 0..8191
        const float4* src = (const float4*)(p1 + (size_t)u * 12);
        float4 a = src[0], b4 = src[1], c4 = src[2];
        float X[4] = {a.x, a.w, b4.z, c4.y};
        float Y[4] = {a.y, b4.x, b4.w, c4.z};
        float Z[4] = {a.z, b4.y, c4.x, c4.w};
        const int pbase = u * 4;
        const int bb = pbase >> 14;
        const unsigned packed = *(const unsigned*)(pslab + pbase);
        #pragma unroll
        for (int i = 0; i < 4; ++i) {
            const int s = (int)((packed >> (8 * i)) & 255u);
            const unsigned start = s ? sg[bb * 256 + s - 1] : 0u;
            const unsigned pos = start + atomicAdd(&gcur[bb * 256 + s], 1u);
            const size_t o = (size_t)bb * NN + pos;
            xs[o] = X[i]; ys[o] = Y[i]; zs[o] = Z[i];
            ns[o] = fmaf(X[i], X[i], fmaf(Y[i], Y[i], Z[i] * Z[i]));
            orig[o] = (pbase + i) & (NN - 1);    // LOCAL original index
        }
    } else {
        const int u = (blockIdx.x - 32) * 256 + t;   // query 0..8191
        const int qb = u >> 12;
        const int sq = (int)qslab[u];
        const unsigned qstart = sq ? sg[512 + qb * 256 + sq - 1] : 0u;
        const unsigned qpos = qstart + atomicAdd(&qcur[qb * 256 + sq], 1u);
        qperm[qb * MM + qpos] = u & (MM - 1);    // local query index, slab-sorted
    }
}

// ---------- fused kNN: slab-window bound -> collect -> select -> gather ----------
// knn body is the round-1 verified version (2048-pt shared phase-1, CAP 192),
// plus a zero-init of sel[] as a safety net against stale-LDS index escape.
__global__ __launch_bounds__(256, 4)
void knn_kernel(const float* __restrict__ xs, const float* __restrict__ ys,
                const float* __restrict__ zs, const float* __restrict__ ns,
                const int* __restrict__ orig, const int* __restrict__ qperm,
                const int* __restrict__ slabSt, const float* __restrict__ p2,
                const unsigned* __restrict__ xt32,
                int* __restrict__ idx_ws, float* __restrict__ out) {
    __shared__ unsigned hist[QW * NBIN];   // 8 KB
    __shared__ u64 col[QW * CAP];          // 6 KB
    __shared__ unsigned colcnt[QW];
    __shared__ float bound_s[QW];
    __shared__ int sel[QW][KK];
    __shared__ float fmean[QW][CC];

    const int t = threadIdx.x;
    const int w = t >> 6;
    const int l = t & 63;
    const int bblk = blockIdx.x >> 10;             // batch (1024 blocks each)
    const int qb4  = (blockIdx.x & 1023) * QW;
    const int* QP  = qperm + bblk * MM;
    const int* SST = slabSt + bblk * 257;
    const float4* X4 = (const float4*)xs + (size_t)bblk * NF4;
    const float4* Y4 = (const float4*)ys + (size_t)bblk * NF4;
    const float4* Z4 = (const float4*)zs + (size_t)bblk * NF4;
    const float4* N4 = (const float4*)ns + (size_t)bblk * NF4;
    const int* ORG = orig + (size_t)bblk * NN;

    float qx[QW], ax[QW], ay[QW], az[QW], qn[QW];
    #pragma unroll
    for (int j = 0; j < QW; ++j) {
        int ql = QP[qb4 + j];
        const float* qp = p2 + ((size_t)bblk * MM + ql) * 3;
        float x = qp[0], y = qp[1], z = qp[2];
        qx[j] = x;
        ax[j] = -2.0f * x; ay[j] = -2.0f * y; az[j] = -2.0f * z;
        qn[j] = fmaf(x, x, fmaf(y, y, z * z));
    }

    #pragma unroll
    for (int i = t; i < QW * NBIN; i += 256) hist[i] = 0u;
    if (t < QW) colcnt[t] = 0u;
    if (t < QW * KK) ((int*)sel)[t] = 0;   // safety: no stale-LDS index escape
    __syncthreads();

    // same distance expression everywhere (bound pass and collect pass)
    #define DISTJ(j, xv, yv, zv, nv) \
        (fmaf(ax[j], xv, fmaf(ay[j], yv, fmaf(az[j], zv, nv))) + qn[j])

    // ---- phase 1: histogram the 2048 x-nearest points (valid-subset bound:
    //      the 16th-smallest over ANY subset upper-bounds the true d16) ----
    {
        int pos = SST[slab_of(qx[0])];
        int S = pos - 1024;
        S = S < 0 ? 0 : (S > NN - 2048 ? NN - 2048 : S);
        const int S4 = S >> 2;
        #define H1(xv, yv, zv, nv)                                              \
        {   _Pragma("unroll")                                                   \
            for (int j = 0; j < QW; ++j) {                                      \
                float d = DISTJ(j, xv, yv, zv, nv);                             \
                int bin = (int)(fkey(d) >> SHIFT) - BOFF;                       \
                bin = bin < 0 ? 0 : (bin > NBIN - 1 ? NBIN - 1 : bin);          \
                atomicAdd(&hist[j * NBIN + bin], 1u);                           \
            } }
        #pragma unroll
        for (int it = 0; it < 2; ++it) {
            int f = S4 + it * 256 + w * 64 + l;
            float4 X = X4[f], Y = Y4[f], Z = Z4[f], Nr = N4[f];
            H1(X.x, Y.x, Z.x, Nr.x) H1(X.y, Y.y, Z.y, Nr.y)
            H1(X.z, Y.z, Z.z, Nr.z) H1(X.w, Y.w, Z.w, Nr.w)
        }
        #undef H1
    }
    __syncthreads();

    // ---- beta for query w (one query per wave) ----
    {
        const unsigned hb = w * NBIN;
        unsigned c8[8], s = 0;
        #pragma unroll
        for (int i = 0; i < 8; ++i) { c8[i] = hist[hb + l * 8 + i]; s += c8[i]; }
        unsigned pre = s;
        #pragma unroll
        for (int off = 1; off < 64; off <<= 1) {
            unsigned o = __shfl_up(pre, off, 64);
            if (l >= off) pre += o;
        }
        unsigned excl = pre - s;
        int bsel = 0x7fffffff;
        if (excl < KK) {
            unsigned cum = excl;
            #pragma unroll
            for (int i = 0; i < 8; ++i) {
                if (cum < KK && cum + c8[i] >= KK) bsel = l * 8 + i;
                cum += c8[i];
            }
        }
        #pragma unroll
        for (int off = 32; off; off >>= 1) {
            int o = __shfl_xor(bsel, off, 64);
            bsel = o < bsel ? o : bsel;
        }
        if (bsel == 0x7fffffff) bsel = NBIN - 1;
        if (l == 0)
            bound_s[w] = __uint_as_float(
                (((unsigned)(bsel + BOFF + 1)) << SHIFT) & 0x7fffffffu);
    }
    __syncthreads();
    float bnd[QW];
    #pragma unroll
    for (int j = 0; j < QW; ++j) bnd[j] = bound_s[j];

    // ---- window: union over 4 queries of [qx - sqrt(bnd), qx + sqrt(bnd)] ----
    float wl = 1e30f, wh = -1e30f;
    #pragma unroll
    for (int j = 0; j < QW; ++j) {
        float b = sqrtf(bnd[j]);
        wl = fminf(wl, qx[j] - b);
        wh = fmaxf(wh, qx[j] + b);
    }
    int sLo = slab_of(wl) - 1; sLo = sLo < 0 ? 0 : sLo;          // +-1 slab safety
    int sHi = slab_of(wh) + 1; sHi = sHi > NSLAB - 1 ? NSLAB - 1 : sHi;
    const int F0 = SST[sLo] >> 2;
    int F1 = (SST[sHi + 1] + 3) >> 2;
    F1 = F1 > NF4 ? NF4 : F1;

    // ---- phase 2: scan window only, collect d < bnd[j] ----
    #define PUSH(j, dv, p)                                                      \
    {   unsigned key = fkey(dv);                                                \
        int oid = ORG[(p)];                                                     \
        unsigned slot = atomicAdd(&colcnt[j], 1u);                              \
        slot = slot < CAP ? slot : CAP - 1;                                     \
        col[(j) * CAP + slot] = ((u64)key << 32) | (unsigned)oid; }

    const int nIt = (F1 - F0 + 255) >> 8;
    #pragma unroll 1
    for (int it = 0; it < nIt; ++it) {
        int f = F0 + it * 256 + w * 64 + l;
        if (f < F1) {
            float4 X = X4[f], Y = Y4[f], Z = Z4[f], Nr = N4[f];
            #pragma unroll
            for (int j = 0; j < QW; ++j) {
                float d0 = DISTJ(j, X.x, Y.x, Z.x, Nr.x);
                float d1 = DISTJ(j, X.y, Y.y, Z.y, Nr.y);
                float d2 = DISTJ(j, X.z, Y.z, Z.z, Nr.z);
                float d3 = DISTJ(j, X.w, Y.w, Z.w, Nr.w);
                float mn = fminf(fminf(d0, d1), fminf(d2, d3));
                if (mn < bnd[j]) {
                    if (d0 < bnd[j]) PUSH(j, d0, f * 4 + 0)
                    if (d1 < bnd[j]) PUSH(j, d1, f * 4 + 1)
                    if (d2 < bnd[j]) PUSH(j, d2, f * 4 + 2)
                    if (d3 < bnd[j]) PUSH(j, d3, f * 4 + 3)
                }
            }
        }
    }
    #undef PUSH
    #undef DISTJ
    __syncthreads();

    // ---- select for query w: exact top-16 on (key, orig-idx) ----
    {
        unsigned cnt = colcnt[w]; cnt = cnt < CAP ? cnt : CAP;
        if (cnt <= 64u) {
            // rank scan: broadcast LDS reads, unique ranks (keys distinct via idx)
            u64 v = ((unsigned)l < cnt) ? col[w * CAP + l] : ~0ull;
            int rank = 0;
            for (unsigned i = 0; i < cnt; ++i)
                rank += (col[w * CAP + i] < v) ? 1 : 0;
            if ((unsigned)l < cnt && rank < KK) {
                int id = (int)(unsigned)(v & 0xFFFFFFFFull);
                if (xt32) sel[w][rank] = id;
                else {
                    int qlw = QP[qb4 + w];
                    idx_ws[((size_t)bblk * MM + qlw) * KK + rank] = id;
                }
            }
        } else {
            u64 v0 = ((unsigned)l       < cnt) ? col[w * CAP + l]       : ~0ull;
            u64 v1 = ((unsigned)l + 64  < cnt) ? col[w * CAP + l + 64]  : ~0ull;
            u64 v2 = ((unsigned)l + 128 < cnt) ? col[w * CAP + l + 128] : ~0ull;
            #pragma unroll 1
            for (int k = 0; k < KK; ++k) {
                u64 m = v0 < v1 ? v0 : v1;
                m = v2 < m ? v2 : m;
                #pragma unroll
                for (int off = 32; off; off >>= 1) {
                    u64 o = __shfl_xor(m, off, 64);
                    m = o < m ? o : m;
                }
                if (v0 == m) v0 = ~0ull;
                if (v1 == m) v1 = ~0ull;
                if (v2 == m) v2 = ~0ull;
                if (l == 0) {
                    int id = (m == ~0ull) ? 0 : (int)(unsigned)(m & 0xFFFFFFFFull);
                    if (xt32) sel[w][k] = id;
                    else {
                        int qlw = QP[qb4 + w];
                        idx_ws[((size_t)bblk * MM + qlw) * KK + k] = id;
                    }
                }
            }
        }
    }
    if (!xt32) return;
    __syncthreads();

    // ---- fused gather from bf16 xt: one wave per query, 4-way k-split ----
    {
        const int cg = l & 15;                 // 4-channel group (uint2 = 8B bf16)
        const int h  = l >> 4;                 // neighbor quarter 0..3
        const unsigned* xb = xt32 + (size_t)bblk * NN * 32 + cg * 2;
        float a0 = 0.f, a1 = 0.f, a2 = 0.f, a3 = 0.f;
        #pragma unroll
        for (int k = 0; k < 4; ++k) {
            int n = sel[w][h * 4 + k];
            uint2 v = *(const uint2*)(xb + (size_t)n * 32);
            a0 += __uint_as_float(v.x << 16);
            a1 += __uint_as_float(v.x & 0xffff0000u);
            a2 += __uint_as_float(v.y << 16);
            a3 += __uint_as_float(v.y & 0xffff0000u);
        }
        a0 += __shfl_xor(a0, 16, 64); a0 += __shfl_xor(a0, 32, 64);
        a1 += __shfl_xor(a1, 16, 64); a1 += __shfl_xor(a1, 32, 64);
        a2 += __shfl_xor(a2, 16, 64); a2 += __shfl_xor(a2, 32, 64);
        a3 += __shfl_xor(a3, 16, 64); a3 += __shfl_xor(a3, 32, 64);
        if (h == 0) {
            fmean[w][cg * 4 + 0] = a0; fmean[w][cg * 4 + 1] = a1;
            fmean[w][cg * 4 + 2] = a2; fmean[w][cg * 4 + 3] = a3;
        }
    }
    __syncthreads();
    {
        const float sc = 1.0f / 16.0f;
        float* ob = out + (size_t)bblk * CC * MM;
        int c = t >> 2;
        int qlj = QP[qb4 + (t & 3)];           // scattered 4B store per query
        ob[(size_t)c * MM + qlj] = fmean[t & 3][c] * sc;
    }
}

// ---------- fallback gather (no xt room): column gather from x1 ----------
#define GM 64
__global__ __launch_bounds__(256)
void gather_kernel(const float* __restrict__ x1, const int* __restrict__ idx_ws,
                   float* __restrict__ out) {
    __shared__ int lidx[KK * GM];
    const int t = threadIdx.x;
    const int mblk = blockIdx.x >> 2;
    const int cblk = blockIdx.x & 3;
    const int m0 = mblk * GM;
    for (int e = t; e < KK * GM; e += 256) {
        int val = idx_ws[m0 * KK + e];
        lidx[(e & 15) * GM + (e >> 4)] = val;
    }
    __syncthreads();
    const int ml = t & 63;
    const int q = m0 + ml, b = q >> 12, mm = q & (MM - 1);
    const float* xb = x1 + (size_t)b * CC * NN;
    float* ob = out + (size_t)b * CC * MM;
    #pragma unroll 1
    for (int r = 0; r < 4; ++r) {
        int c = cblk * 16 + (t >> 6) * 4 + r;
        const float* xc = xb + (size_t)c * NN;
        float acc = 0.f;
        #pragma unroll
        for (int k = 0; k < KK; ++k) acc += xc[lidx[k * GM + ml]];
        ob[(size_t)c * MM + mm] = acc * (1.0f / 16.0f);
    }
}

extern "C" void kernel_launch(void* const* d_in, const int* in_sizes, int n_in,
                              void* d_out, int out_size, void* d_ws, size_t ws_size,
                              hipStream_t stream) {
    const float* p1 = (const float*)d_in[0];   // (B,N,3)
    const float* x1 = (const float*)d_in[1];   // (B,C,N)
    const float* p2 = (const float*)d_in[2];   // (B,M,3)
    float* out = (float*)d_out;                // (B,C,M)

    char* ws = (char*)d_ws;
    // sorted SoA: xs,ys,zs,ns each BB*NN floats = 512 KB total
    float* xs  = (float*)ws;
    float* ysv = xs + BB * NN;
    float* zsv = ysv + BB * NN;
    float* nsv = zsv + BB * NN;
    int* orig  = (int*)(ws + 524288);                    // 128 KB
    int* qperm = (int*)(ws + 655360);                    // 32 KB
    unsigned char* pslab = (unsigned char*)(ws + 688128);// 32 KB
    unsigned char* qslab = (unsigned char*)(ws + 720896);// 8 KB
    unsigned* ppart = (unsigned*)(ws + 729088);          // 32 KB (32x256)
    unsigned* qpart = (unsigned*)(ws + 761856);          // 32 KB (32x256)
    unsigned* gcur  = (unsigned*)(ws + 794624);          // 2 KB (zeroed in prep)
    unsigned* qcur  = (unsigned*)(ws + 796672);          // 2 KB (zeroed in prep)
    int* slabSt = (int*)(ws + 798720);                   // 2*257 ints (pad 4 KB)
    const size_t xt_off   = 802816;
    const size_t xt_bytes = (size_t)BB * NN * CC * 2;    // 4.19 MB bf16
    const bool use_t = ws_size >= xt_off + xt_bytes;
    unsigned* xt32 = use_t ? (unsigned*)(ws + xt_off) : nullptr;
    int* idx_ws = use_t ? nullptr : (int*)(ws + xt_off); // 512 KB fallback

    prep_kernel<<<544, 256, 0, stream>>>(p1, x1, p2, ppart, qpart, gcur, qcur,
                                         pslab, qslab, xt32, use_t ? 1 : 0);
    scatter_kernel<<<64, 256, 0, stream>>>(p1, ppart, qpart, gcur, qcur,
                                           pslab, qslab, slabSt,
                                           xs, ysv, zsv, nsv, orig, qperm);
    knn_kernel<<<NQ / QW, 256, 0, stream>>>(xs, ysv, zsv, nsv, orig, qperm,
                                            slabSt, p2, xt32, idx_ws, out);
    if (!use_t)
        gather_kernel<<<(NQ / GM) * 4, 256, 0, stream>>>(x1, idx_ws, out);
}